// Round 7
// baseline (39.689 us; speedup 1.0000x reference)
//
#include <hip/hip_runtime.h>

namespace {

constexpr int kT   = 8;    // timesteps
constexpr int kB   = 256;  // batch
constexpr int kNQ  = 8;    // qubits per circuit
constexpr int kNB  = 8;    // blocks
constexpr int kD   = 64;   // features
constexpr int kNL  = 2;    // quantum layers
constexpr int kCirc = kT * kNB;        // 64 circuits per layer
constexpr int kGates = 2 * kNQ;        // 16 Rot gates per circuit
constexpr int kGateF = 8;

// ---------------- Rot-gate precompute ----------------
__global__ void precompute_gates(const float* __restrict__ theta, float* __restrict__ gt) {
    int i = blockIdx.x * blockDim.x + threadIdx.x;
    if (i >= kNL * kCirc * kGates) return;
    int g = i & 15;
    int c = (i >> 4) & 63;
    int l = i >> 10;
    int t = c >> 3, u = c & 7;
    int d = g >> 3, w = g & 7;
    const float* th = theta + ((((t * kNL + l) * kNB + u) * 2 + d) * kNQ + w) * 3;
    float phi = th[0], tht = th[1], omg = th[2];
    float st, ct, sp, cp, sm, cm;
    __sincosf(0.5f * tht, &st, &ct);
    __sincosf(0.5f * (phi + omg), &sp, &cp);
    __sincosf(0.5f * (phi - omg), &sm, &cm);
    float* o = gt + i * kGateF;
    o[0] =  ct * cp;  o[1] = -ct * sp;
    o[2] = -st * cm;  o[3] = -st * sm;
    o[4] =  st * cm;  o[5] = -st * sm;
    o[6] =  ct * cp;  o[7] =  ct * sp;
}

// ---------------- shuffle backends ----------------
template <int CTRL>
__device__ __forceinline__ float f_dpp(float x) {
    return __builtin_bit_cast(float, __builtin_amdgcn_update_dpp(
        0, __builtin_bit_cast(int, x), CTRL, 0xF, 0xF, true));
}
constexpr int kDppXor1 = 0xB1;   // quad_perm [1,0,3,2]  = lane^1
constexpr int kDppXor2 = 0x4E;   // quad_perm [2,3,0,1]  = lane^2
constexpr int kDppXor8 = 0x128;  // row_ror:8 (16-lane row, rot-by-8 == lane^8)

// partner fetch at lane distance 1<<MODE: 0,1,3 via DPP (VALU); 2 via shfl (DS)
template <int MODE>
__device__ __forceinline__ float lane_partner(float x) {
    if constexpr (MODE == 0) return f_dpp<kDppXor1>(x);
    else if constexpr (MODE == 1) return f_dpp<kDppXor2>(x);
    else if constexpr (MODE == 3) return f_dpp<kDppXor8>(x);
    else return __shfl_xor(x, 4, 64);
}

// pair-sum across lane^16 / lane^32 — validated __shfl_xor backend.
// (permlane*_swap attempts failed twice: builtin self-input degenerates via
//  register coalescing (round 3, absmax 3.95 = x4 scale) and raw inline asm
//  killed the build entirely (round 6, zero output). Do not retry without an
//  isolated probe.)
template <bool IS32>
__device__ __forceinline__ float plsum(float x) {
    return x + __shfl_xor(x, IS32 ? 32 : 16, 64);
}

// ---------------- gate helpers (2 samples/wave, 4 amps/lane) ----------------
// amp index k = (lane<<2)|reg; wire w -> index bit 7-w.
// wires 0..5 -> lane bits 5..0; wires 6,7 -> reg bits 1,0.

template <int MODE>
__device__ __forceinline__ void gate_direct(float (&re)[2][4], float (&im)[2][4], int bit,
                                            const float* __restrict__ gp) {
    const float aR = bit ? gp[6] : gp[0];
    const float aI = bit ? gp[7] : gp[1];
    const float bR = bit ? gp[4] : gp[2];
    const float bI = bit ? gp[5] : gp[3];
#pragma unroll
    for (int s = 0; s < 2; ++s)
#pragma unroll
        for (int r = 0; r < 4; ++r) {
            const float pre = lane_partner<MODE>(re[s][r]);
            const float pim = lane_partner<MODE>(im[s][r]);
            const float mre = re[s][r], mim = im[s][r];
            re[s][r] = aR * mre - aI * mim + bR * pre - bI * pim;
            im[s][r] = aR * mim + aI * mre + bR * pim + bI * pre;
        }
}

// pair-sum lane gate (xor16/xor32): new = cA*m + cB*partner = (cA-cB)*m + cB*(m+partner)
template <bool IS32>
__device__ __forceinline__ void gate_psum(float (&re)[2][4], float (&im)[2][4], int bit,
                                          const float* __restrict__ gp) {
    const float aR = bit ? (gp[6] - gp[4]) : (gp[0] - gp[2]);
    const float aI = bit ? (gp[7] - gp[5]) : (gp[1] - gp[3]);
    const float bR = bit ? gp[4] : gp[2];
    const float bI = bit ? gp[5] : gp[3];
#pragma unroll
    for (int s = 0; s < 2; ++s)
#pragma unroll
        for (int r = 0; r < 4; ++r) {
            const float tre = plsum<IS32>(re[s][r]);
            const float tim = plsum<IS32>(im[s][r]);
            const float mre = re[s][r], mim = im[s][r];
            re[s][r] = aR * mre - aI * mim + bR * tre - bI * tim;
            im[s][r] = aR * mim + aI * mre + bR * tim + bI * tre;
        }
}

// register-bit gate (wires 6,7)
template <int PB>
__device__ __forceinline__ void cgate_reg2(float (&re)[2][4], float (&im)[2][4],
                                           const float* __restrict__ gp) {
    const float u00r = gp[0], u00i = gp[1], u01r = gp[2], u01i = gp[3];
    const float u10r = gp[4], u10i = gp[5], u11r = gp[6], u11i = gp[7];
#pragma unroll
    for (int s = 0; s < 2; ++s)
#pragma unroll
        for (int lo = 0; lo < 4; ++lo) {
            if (lo & (1 << PB)) continue;
            const int hi = lo | (1 << PB);
            const float lre = re[s][lo], lim = im[s][lo];
            const float hre = re[s][hi], him = im[s][hi];
            re[s][lo] = u00r * lre - u00i * lim + u01r * hre - u01i * him;
            im[s][lo] = u00r * lim + u00i * lre + u01r * him + u01i * hre;
            re[s][hi] = u10r * lre - u10i * lim + u11r * hre - u11i * him;
            im[s][hi] = u10r * lim + u10i * lre + u11r * him + u11i * hre;
        }
}

// ---------------- one circuit sim: 2 samples, output = 3 Walsh streams ----------------
// State after AngleEmbedding + depth-0 Rot + CNOT-ring1 built directly as a permuted
// spinor product; depth-1 Rot gates applied; CNOT-ring2 folded into Walsh parities.
__device__ __forceinline__ void sim2(const float (&ang)[2][8],
                                     const float* __restrict__ g0,
                                     const float* __restrict__ g1,
                                     int lane, const unsigned (&sg)[4],
                                     float bf4, float bf5,
                                     float (&WP)[2], float (&WR1)[2], float (&WR0)[2]) {
    const int l0 = lane & 1,        l1 = (lane >> 1) & 1, l2 = (lane >> 2) & 1;
    const int l3 = (lane >> 3) & 1, l4 = (lane >> 4) & 1, l5 = (lane >> 5) & 1;

    float re[2][4], im[2][4];
#pragma unroll
    for (int s = 0; s < 2; ++s) {
        // per-wire spinor after RY(ang) then d0 Rot
        float spr[8][2], spi[8][2];
#pragma unroll
        for (int w = 0; w < 8; ++w) {
            float sn, cs;
            __sincosf(0.5f * ang[s][w], &sn, &cs);
            const float* gp = g0 + w * kGateF;
            spr[w][0] = gp[0] * cs + gp[2] * sn;
            spi[w][0] = gp[1] * cs + gp[3] * sn;
            spr[w][1] = gp[4] * cs + gp[6] * sn;
            spi[w][1] = gp[5] * cs + gp[7] * sn;
        }
        // ring1 inverse bit map (x = pre-ring1 wire bits; (lane,reg) = post-ring1):
        //  x0=l5^r0  x1=l5^l4^r0  x2=l4^l3  x3=l3^l2  x4=l2^l1  x5=l1^l0
        //  x6=l0^r1  x7=r1^r0
        const int x2 = l4 ^ l3, x3 = l3 ^ l2, x4 = l2 ^ l1, x5 = l1 ^ l0;
        float t1r, t1i, t2r, t2i;
        {
            const float ar = x2 ? spr[2][1] : spr[2][0], ai = x2 ? spi[2][1] : spi[2][0];
            const float br = x3 ? spr[3][1] : spr[3][0], bi = x3 ? spi[3][1] : spi[3][0];
            t1r = ar * br - ai * bi; t1i = ar * bi + ai * br;
        }
        {
            const float ar = x4 ? spr[4][1] : spr[4][0], ai = x4 ? spi[4][1] : spi[4][0];
            const float br = x5 ? spr[5][1] : spr[5][0], bi = x5 ? spi[5][1] : spi[5][0];
            t2r = ar * br - ai * bi; t2i = ar * bi + ai * br;
        }
        const float Lr = t1r * t2r - t1i * t2i, Li = t1r * t2i + t1i * t2r;
        // Q(r0) = s0[l5^r0] * s1[l5^l4^r0]
        const int xa = l5, xb = l5 ^ l4;
        const float a0r = xa ? spr[0][1] : spr[0][0], a0i = xa ? spi[0][1] : spi[0][0];
        const float a1r = xa ? spr[0][0] : spr[0][1], a1i = xa ? spi[0][0] : spi[0][1];
        const float b0r = xb ? spr[1][1] : spr[1][0], b0i = xb ? spi[1][1] : spi[1][0];
        const float b1r = xb ? spr[1][0] : spr[1][1], b1i = xb ? spi[1][0] : spi[1][1];
        const float Q0r = a0r * b0r - a0i * b0i, Q0i = a0r * b0i + a0i * b0r;
        const float Q1r = a1r * b1r - a1i * b1i, Q1i = a1r * b1i + a1i * b1r;
        // R(r1) = s6[l0^r1]; S(r0,r1) = s7[r1^r0]
        const float R0r = l0 ? spr[6][1] : spr[6][0], R0i = l0 ? spi[6][1] : spi[6][0];
        const float R1r = l0 ? spr[6][0] : spr[6][1], R1i = l0 ? spi[6][0] : spi[6][1];
        const float S0r = spr[7][0], S0i = spi[7][0];
        const float S1r = spr[7][1], S1i = spi[7][1];
        float RSr[4], RSi[4];
        RSr[0] = R0r * S0r - R0i * S0i; RSi[0] = R0r * S0i + R0i * S0r;  // r=0
        RSr[1] = R0r * S1r - R0i * S1i; RSi[1] = R0r * S1i + R0i * S1r;  // r=1
        RSr[2] = R1r * S1r - R1i * S1i; RSi[2] = R1r * S1i + R1i * S1r;  // r=2
        RSr[3] = R1r * S0r - R1i * S0i; RSi[3] = R1r * S0i + R1i * S0r;  // r=3
        const float LQ0r = Lr * Q0r - Li * Q0i, LQ0i = Lr * Q0i + Li * Q0r;
        const float LQ1r = Lr * Q1r - Li * Q1i, LQ1i = Lr * Q1i + Li * Q1r;
        re[s][0] = LQ0r * RSr[0] - LQ0i * RSi[0]; im[s][0] = LQ0r * RSi[0] + LQ0i * RSr[0];
        re[s][1] = LQ1r * RSr[1] - LQ1i * RSi[1]; im[s][1] = LQ1r * RSi[1] + LQ1i * RSr[1];
        re[s][2] = LQ0r * RSr[2] - LQ0i * RSi[2]; im[s][2] = LQ0r * RSi[2] + LQ0i * RSr[2];
        re[s][3] = LQ1r * RSr[3] - LQ1i * RSi[3]; im[s][3] = LQ1r * RSi[3] + LQ1i * RSr[3];
    }

    // --- depth-1 Rot gates (wire w on lane bit 5-w) ---
    gate_psum<true >(re, im, l5, g1 + 0 * kGateF);   // wire0: xor32 (shfl pair-sum)
    gate_psum<false>(re, im, l4, g1 + 1 * kGateF);   // wire1: xor16 (shfl pair-sum)
    gate_direct<3>(re, im, l3, g1 + 2 * kGateF);     // wire2: xor8 (DPP row_ror:8)
    gate_direct<2>(re, im, l2, g1 + 3 * kGateF);     // wire3: xor4 (shfl)
    gate_direct<1>(re, im, l1, g1 + 4 * kGateF);     // wire4: xor2 (DPP)
    gate_direct<0>(re, im, l0, g1 + 5 * kGateF);     // wire5: xor1 (DPP)
    cgate_reg2<1>(re, im, g1 + 6 * kGateF);          // wire6: reg bit 1
    cgate_reg2<0>(re, im, g1 + 7 * kGateF);          // wire7: reg bit 0

    // --- ring2 folded into Walsh parities: E_w = W_stream[mask_w] ---
    // Full WHT butterfly leaves W[m] at lane m for each stream.
    // levels 0,1,3: DPP partner + sign; level 2: shfl; levels 4,5: psum - bf*v.
#pragma unroll
    for (int s = 0; s < 2; ++s) {
        const float p0 = re[s][0] * re[s][0] + im[s][0] * im[s][0];
        const float p1 = re[s][1] * re[s][1] + im[s][1] * im[s][1];
        const float p2 = re[s][2] * re[s][2] + im[s][2] * im[s][2];
        const float p3 = re[s][3] * re[s][3] + im[s][3] * im[s][3];
        float P  = (p0 + p1) + (p2 + p3);   // no reg sign
        float R1 = (p0 + p1) - (p2 + p3);   // reg-bit-1 sign
        float R0 = (p0 - p1) + (p2 - p3);   // reg-bit-0 sign
#pragma unroll
        for (int st = 0; st < 3; ++st) {
            float v = (st == 0) ? P : (st == 1) ? R1 : R0;
            float d;
            d = f_dpp<kDppXor1>(v);
            v = d + __builtin_bit_cast(float, __builtin_bit_cast(unsigned, v) ^ sg[0]);
            d = f_dpp<kDppXor2>(v);
            v = d + __builtin_bit_cast(float, __builtin_bit_cast(unsigned, v) ^ sg[1]);
            d = __shfl_xor(v, 4, 64);
            v = d + __builtin_bit_cast(float, __builtin_bit_cast(unsigned, v) ^ sg[2]);
            d = f_dpp<kDppXor8>(v);
            v = d + __builtin_bit_cast(float, __builtin_bit_cast(unsigned, v) ^ sg[3]);
            d = plsum<false>(v); v = d - bf4 * v;
            d = plsum<true >(v); v = d - bf5 * v;
            if (st == 0) P = v; else if (st == 1) R1 = v; else R0 = v;
        }
        WP[s] = P; WR1[s] = R1; WR0[s] = R0;
    }
}

// scatter the 8 expvals (E_w = Walsh coeffs at fixed lanes) to e[0..7]
// masks: E0:R1@10  E1:R0@5  E2:P@40  E3:P@20  E4:P@42  E5:P@21  E6:R1@42  E7:R0@21
template <typename PT>
__device__ __forceinline__ void scatter_ev(PT e, int lane, float P, float R1, float R0) {
    if (lane == 10) e[0] = R1;
    if (lane ==  5) e[1] = R0;
    if (lane == 40) e[2] = P;
    if (lane == 20) e[3] = P;
    if (lane == 42) { e[4] = P; e[6] = R1; }
    if (lane == 21) { e[5] = P; e[7] = R0; }
}

// ---------------- fused both-layer kernel ----------------
// block = 512 threads = 8 waves = the 8 circuits of one (t, sample-pair);
// layer-0 results exchanged through 512 B of LDS.
__global__ __launch_bounds__(512) void fused_kernel(const float* __restrict__ x,
                                                    const float* __restrict__ gt,
                                                    float* __restrict__ out) {
    const int widx = __builtin_amdgcn_readfirstlane(threadIdx.x >> 6);  // circuit u
    const int lane = threadIdx.x & 63;
    const int tt = blockIdx.x >> 7;          // timestep
    const int b0 = (blockIdx.x & 127) << 1;  // first sample of pair

    __shared__ float exch[2][8][8];          // [sample][block i][wire w]

    unsigned sg[4];
#pragma unroll
    for (int q = 0; q < 4; ++q) sg[q] = ((lane >> q) & 1u) << 31;
    const float bf4 = ((lane >> 4) & 1) ? 2.0f : 0.0f;
    const float bf5 = ((lane >> 5) & 1) ? 2.0f : 0.0f;

    const int c = tt * kNB + widx;
    float WP[2], WR1[2], WR0[2];
    float ang[2][8];

    // ---- phase 0: layer-0 circuit (t, widx), samples b0, b0+1 ----
    {
        const float* g0 = gt + (size_t)c * kGates * kGateF;
        const float* g1 = g0 + 8 * kGateF;
#pragma unroll
        for (int s = 0; s < 2; ++s) {
            const float* ab = x + ((b0 + s) * kT + tt) * kD + widx * kNQ;
#pragma unroll
            for (int w = 0; w < 8; ++w) ang[s][w] = ab[w];
        }
        sim2(ang, g0, g1, lane, sg, bf4, bf5, WP, WR1, WR0);
#pragma unroll
        for (int s = 0; s < 2; ++s)
            scatter_ev(&exch[s][widx][0], lane, WP[s], WR1[s], WR0[s]);
    }
    __syncthreads();
    // ---- phase 1: layer-1 circuit (t, widx) gathers feature widx of every block ----
    {
        const float* g0 = gt + (size_t)(kCirc + c) * kGates * kGateF;
        const float* g1 = g0 + 8 * kGateF;
#pragma unroll
        for (int s = 0; s < 2; ++s)
#pragma unroll
            for (int i = 0; i < 8; ++i) ang[s][i] = exch[s][i][widx];
        sim2(ang, g0, g1, lane, sg, bf4, bf5, WP, WR1, WR0);
#pragma unroll
        for (int s = 0; s < 2; ++s)
            scatter_ev(out + ((b0 + s) * kT + tt) * kD + widx * kNQ, lane,
                       WP[s], WR1[s], WR0[s]);
    }
}

}  // namespace

extern "C" void kernel_launch(void* const* d_in, const int* in_sizes, int n_in,
                              void* d_out, int out_size, void* d_ws, size_t ws_size,
                              hipStream_t stream) {
    const float* x     = (const float*)d_in[0];   // (B, T, D) fp32
    const float* theta = (const float*)d_in[1];   // (T, NL, NB, DEPTH, NQ, 3) fp32
    float* out = (float*)d_out;                   // (B, T, D) fp32

    float* gt = (float*)d_ws;                     // gate table: 2*64*16*8 floats (64 KB)

    precompute_gates<<<(kNL * kCirc * kGates + 255) / 256, 256, 0, stream>>>(theta, gt);
    // 8 timesteps x 128 sample-pairs; 512 threads = 8 circuits x (2 samples/wave)
    fused_kernel<<<kT * (kB / 2), 512, 0, stream>>>(x, gt, out);
}